// Round 4
// baseline (1702.326 us; speedup 1.0000x reference)
//
#include <hip/hip_runtime.h>
#include <cstdint>
#include <cstddef>

// Problem constants
#define OBS_DIMM 128
#define PROJJ    64
#define HIDD     256
#define LATT     24
#define BBATCH   1024
#define TTIME    256
#define KDIM     384   // 128 obs-cols + 256 h-cols
#define NGATE    768   // 3*HID
#define MBLK     32    // batches per block
#define CHUNK    16    // timesteps per block
#define NGROUP   32
#define NCHUNK   16
#define XSTRIDE  392   // 384 + 8 pad (bf16 elems)
#define MSTRIDE  264   // 256 + 8 pad

using bf16x8 = __attribute__((ext_vector_type(8))) short;   // 8 bf16 in 4 VGPRs
using f32x4  = __attribute__((ext_vector_type(4))) float;

static __device__ __forceinline__ unsigned short f2bf(float f) {
    unsigned u = __builtin_bit_cast(unsigned, f);
    u += 0x7fffu + ((u >> 16) & 1u);          // RNE
    return (unsigned short)(u >> 16);
}
static __device__ __forceinline__ float bf2f(unsigned short h) {
    return __builtin_bit_cast(float, ((unsigned)h) << 16);
}
static __device__ __forceinline__ float fexp2(float x) { return __builtin_amdgcn_exp2f(x); }
static __device__ __forceinline__ float flog2(float x) { return __builtin_amdgcn_logf(x); }
static __device__ __forceinline__ float frcp (float x) { return __builtin_amdgcn_rcpf(x); }
static __device__ __forceinline__ float sigmoid_(float x) { return frcp(1.f + fexp2(-1.44269504f * x)); }
static __device__ __forceinline__ float tanh_(float x)    { return 1.f - 2.f * frcp(fexp2(2.88539008f * x) + 1.f); }

#define MFMA16(a, b, c) __builtin_amdgcn_mfma_f32_16x16x32_bf16((a), (b), (c), 0, 0, 0)

// ---------------------------------------------------------------------------
// Prep: fused weight W' = [[W_in@W_ih],[W_hh]] (384x768) in per-wave
// contiguous stream layout (72 KB per wave, sequential in access order):
//   idx = ((w*12 + ks)*6 + i*3 + gate)*512 + lane*8 + jj
// wave w owns hidden units [32w,32w+32): col n = gate*256 + (2w+i)*16 + c16,
// k = ks*32 + q*8 + jj, lane = q*16 + c16.
// Also: swizzled W_out (256x32, cols>=24 zero) and b_x = b_in@W_ih + b_ih.
// ---------------------------------------------------------------------------
__global__ void prep_kernel(const float* __restrict__ W_in, const float* __restrict__ b_in,
                            const float* __restrict__ W_ih, const float* __restrict__ b_ih,
                            const float* __restrict__ W_hh, const float* __restrict__ W_out,
                            unsigned short* __restrict__ wsW, unsigned short* __restrict__ wsWo,
                            float* __restrict__ wsBx) {
    int idx = blockIdx.x * 256 + threadIdx.x;
    if (idx < KDIM * NGATE) {
        int k = idx / NGATE, n = idx - k * NGATE;
        float s;
        if (k < OBS_DIMM) {
            s = 0.f;
            for (int j = 0; j < PROJJ; ++j) s += W_in[k * PROJJ + j] * W_ih[j * NGATE + n];
        } else {
            s = W_hh[(k - OBS_DIMM) * NGATE + n];
        }
        int ks = k >> 5, q = (k >> 3) & 3, jj = k & 7;
        int g = n >> 8, u = n & 255, w = u >> 5, i = (u >> 4) & 1, c16 = u & 15;
        int lane = q * 16 + c16;
        wsW[((w * 12 + ks) * 6 + i * 3 + g) * 512 + lane * 8 + jj] = f2bf(s);
    } else if (idx < KDIM * NGATE + 256 * 32) {
        int i2 = idx - KDIM * NGATE;
        int k = i2 >> 5, n = i2 & 31;
        float s = (n < LATT) ? W_out[k * LATT + n] : 0.f;
        int nt = n >> 4, nl = n & 15, ks = k >> 5, q = (k >> 3) & 3, jj = k & 7;
        wsWo[(nt * 8 + ks) * 512 + (q * 16 + nl) * 8 + jj] = f2bf(s);
    } else if (idx < KDIM * NGATE + 256 * 32 + NGATE) {
        int n = idx - (KDIM * NGATE + 256 * 32);
        float s = b_ih[n];
        for (int j = 0; j < PROJJ; ++j) s += b_in[j] * W_ih[j * NGATE + n];
        wsBx[n] = s;
    }
}

// ---------------------------------------------------------------------------
// Main: grid = 32 batch-groups x 16 time-chunks = 512 blocks = 2 blocks/CU
// (4 waves/SIMD: latency hiding via TLP — R1-R3 ran at 2 waves/SIMD and were
// issue-starved at ~21% combined pipe utilization). __launch_bounds__(512,4)
// caps VGPR at 128 so two 8-wave blocks co-reside; LDS 70.6 KB/block.
// ---------------------------------------------------------------------------
__global__ __launch_bounds__(512, 4)
void gru_kernel(const float* __restrict__ obs, const int* __restrict__ is_init,
                const float* __restrict__ hx, const float* __restrict__ b_hh,
                const float* __restrict__ b_out,
                const unsigned short* __restrict__ wsW, const unsigned short* __restrict__ wsWo,
                const float* __restrict__ wsBx,
                float* __restrict__ out, float* __restrict__ hfin) {
    __shared__ __align__(16) unsigned short sX[MBLK * XSTRIDE];   // [obs_t bf16 | h bf16]
    __shared__ __align__(16) unsigned short sM[MBLK * MSTRIDE];   // mish(h_new) bf16
    __shared__ __align__(16) unsigned short sWo[16 * 512];        // W_out fragments
    __shared__ __align__(16) float sOut[4 * MBLK * LATT];         // 4-step output stage
    __shared__ int sT;

    const int tid  = threadIdx.x;
    const int w    = tid >> 6;
    const int lane = tid & 63;
    const int q    = lane >> 4;
    const int c16  = lane & 15;
    const int bid  = blockIdx.x;
    const int g    = bid & (NGROUP - 1);
    const int ch   = bid >> 5;
    const int b0   = g * MBLK;
    const int t0   = ch * CHUNK;

    // stage W_out fragments into LDS (8192 ushorts)
    {
        const uint4* src = (const uint4*)(wsWo);
        uint4* dst = (uint4*)(sWo);
        dst[tid * 2]     = src[tid * 2];
        dst[tid * 2 + 1] = src[tid * 2 + 1];
    }

    // per-wave biases (col = (2w+i)*16 + c16)
    float bR[2], bZ[2], bXN[2], bHN[2];
#pragma unroll
    for (int i = 0; i < 2; ++i) {
        int u = (2 * w + i) * 16 + c16;
        bR[i]  = wsBx[u] + b_hh[u];
        bZ[i]  = wsBx[HIDD + u] + b_hh[HIDD + u];
        bXN[i] = wsBx[2 * HIDD + u];
        bHN[i] = b_hh[2 * HIDD + u];
    }
    float bOutV;
    {
        int col = (w & 1) * 16 + c16;
        bOutV = (col < LATT) ? b_out[col] : 0.f;
    }

    // ---- find start time: most recent reset before t0 (min over group) ----
    if (tid == 0) sT = (ch == 0) ? 0 : 0x7fffffff;
    __syncthreads();
    if (ch > 0 && tid < MBLK) {
        int b = b0 + tid, fs = 0;
        for (int t = t0 - 1; t > 0; --t) {
            if (is_init[b * TTIME + t] != 0) { fs = t; break; }
        }
        atomicMin(&sT, fs);
    }
    __syncthreads();
    const int tstart = sT;

    // ---- init hidden part of X: hx if starting at t=0, else 0
    {
        int bl = tid >> 4, part = tid & 15;
        bf16x8 v0 = {0, 0, 0, 0, 0, 0, 0, 0}, v1 = {0, 0, 0, 0, 0, 0, 0, 0};
        if (tstart == 0) {
            const float* hp = hx + (size_t)(b0 + bl) * HIDD + part * 16;
#pragma unroll
            for (int ii = 0; ii < 8; ++ii) {
                v0[ii] = (short)f2bf(hp[ii]);
                v1[ii] = (short)f2bf(hp[8 + ii]);
            }
        }
        *(bf16x8*)(sX + bl * XSTRIDE + OBS_DIMM + part * 16)     = v0;
        *(bf16x8*)(sX + bl * XSTRIDE + OBS_DIMM + part * 16 + 8) = v1;
    }
    __syncthreads();

    const unsigned short* wb = wsW + (size_t)w * 36864 + lane * 8;  // per-wave stream base
    const int tend = t0 + CHUNK;

    for (int t = tstart; t < tend; ++t) {
        // ---- phase 1: stage obs_t (bf16) into X cols [0,128); reset-mask h
        {
            int bl = tid >> 4, part = tid & 15;
            const float* op = obs + ((size_t)((b0 + bl) * TTIME + t)) * OBS_DIMM + part * 8;
            float4 a = *(const float4*)op;
            float4 b = *(const float4*)(op + 4);
            bf16x8 pk;
            pk[0] = (short)f2bf(a.x); pk[1] = (short)f2bf(a.y);
            pk[2] = (short)f2bf(a.z); pk[3] = (short)f2bf(a.w);
            pk[4] = (short)f2bf(b.x); pk[5] = (short)f2bf(b.y);
            pk[6] = (short)f2bf(b.z); pk[7] = (short)f2bf(b.w);
            *(bf16x8*)(sX + bl * XSTRIDE + part * 8) = pk;
            if (is_init[(b0 + bl) * TTIME + t] != 0) {
                bf16x8 z8 = {0, 0, 0, 0, 0, 0, 0, 0};
                *(bf16x8*)(sX + bl * XSTRIDE + OBS_DIMM + part * 16)     = z8;
                *(bf16x8*)(sX + bl * XSTRIDE + OBS_DIMM + part * 16 + 8) = z8;
            }
        }
        __syncthreads();

        // ---- phase 2: gates[32,768] = [obs|h] @ W' (K=384), n-gate split at k=128
        f32x4 accR[2][2], accZ[2][2], accXN[2][2], accHN[2][2];
#pragma unroll
        for (int mt = 0; mt < 2; ++mt)
#pragma unroll
            for (int i = 0; i < 2; ++i) {
                accR[mt][i]  = (f32x4){bR[i], bR[i], bR[i], bR[i]};
                accZ[mt][i]  = (f32x4){bZ[i], bZ[i], bZ[i], bZ[i]};
                accXN[mt][i] = (f32x4){bXN[i], bXN[i], bXN[i], bXN[i]};
                accHN[mt][i] = (f32x4){bHN[i], bHN[i], bHN[i], bHN[i]};
            }
#pragma unroll
        for (int ks = 0; ks < 12; ++ks) {
            bf16x8 fw[6];
#pragma unroll
            for (int j = 0; j < 6; ++j)
                fw[j] = *(const bf16x8*)(wb + ((size_t)(ks * 6 + j)) * 512);
            bf16x8 a0 = *(const bf16x8*)(sX + c16 * XSTRIDE + ks * 32 + q * 8);
            bf16x8 a1 = *(const bf16x8*)(sX + (16 + c16) * XSTRIDE + ks * 32 + q * 8);
#pragma unroll
            for (int i = 0; i < 2; ++i) {
                accR[0][i] = MFMA16(a0, fw[i * 3 + 0], accR[0][i]);
                accR[1][i] = MFMA16(a1, fw[i * 3 + 0], accR[1][i]);
                accZ[0][i] = MFMA16(a0, fw[i * 3 + 1], accZ[0][i]);
                accZ[1][i] = MFMA16(a1, fw[i * 3 + 1], accZ[1][i]);
                if (ks < 4) {
                    accXN[0][i] = MFMA16(a0, fw[i * 3 + 2], accXN[0][i]);
                    accXN[1][i] = MFMA16(a1, fw[i * 3 + 2], accXN[1][i]);
                } else {
                    accHN[0][i] = MFMA16(a0, fw[i * 3 + 2], accHN[0][i]);
                    accHN[1][i] = MFMA16(a1, fw[i * 3 + 2], accHN[1][i]);
                }
            }
        }
        __syncthreads();  // A-frag reads of X done before h is overwritten

        // ---- phase 3: wave-local gates + h update (+ mish only when emitting)
        const bool emit = (t >= t0);
#pragma unroll
        for (int mt = 0; mt < 2; ++mt)
#pragma unroll
            for (int i = 0; i < 2; ++i) {
                int u = (2 * w + i) * 16 + c16;
#pragma unroll
                for (int r = 0; r < 4; ++r) {
                    int bl = mt * 16 + q * 4 + r;
                    float rr = sigmoid_(accR[mt][i][r]);
                    float zz = sigmoid_(accZ[mt][i][r]);
                    float nn = tanh_(accXN[mt][i][r] + rr * accHN[mt][i][r]);
                    float hOld = bf2f(sX[bl * XSTRIDE + OBS_DIMM + u]);
                    float hN = (1.f - zz) * nn + zz * hOld;
                    sX[bl * XSTRIDE + OBS_DIMM + u] = f2bf(hN);
                    if (emit) {
                        float sp = 0.69314718f * flog2(1.f + fexp2(1.44269504f * hN));
                        sM[bl * MSTRIDE + u] = f2bf(hN * tanh_(sp));
                    }
                }
            }
        __syncthreads();  // mish + h_new visible

        // ---- phase 4: out-tile GEMM into LDS stage (waves 0..3, own chunk only)
        if (emit && w < 4) {
            int mto = w >> 1, nto = w & 1;
            f32x4 acc = (f32x4){bOutV, bOutV, bOutV, bOutV};
#pragma unroll
            for (int ks = 0; ks < 8; ++ks) {
                bf16x8 a  = *(const bf16x8*)(sM + (mto * 16 + c16) * MSTRIDE + ks * 32 + q * 8);
                bf16x8 wf = *(const bf16x8*)(sWo + (nto * 8 + ks) * 512 + lane * 8);
                acc = MFMA16(a, wf, acc);
            }
            int col = nto * 16 + c16;
            if (col < LATT) {
                int dt = (t - t0) & 3;
#pragma unroll
                for (int r = 0; r < 4; ++r) {
                    int bl = mto * 16 + q * 4 + r;
                    sOut[(dt * MBLK + bl) * LATT + col] = acc[r];
                }
            }
        }

        // ---- flush 4 staged timesteps as coalesced lines (block-uniform path)
        if (emit && ((t - t0) & 3) == 3) {
            __syncthreads();
            int tf = t - 3;
#pragma unroll
            for (int p = 0; p < 6; ++p) {
                int v = p * 512 + tid;            // 0..3071
                int b = v / 96, rr = v - 96 * b;  // rr = dt*24 + col
                int dt = rr / 24, col = rr - 24 * dt;
                out[((size_t)(b0 + b) * TTIME + tf + dt) * LATT + col] =
                    sOut[(dt * MBLK + b) * LATT + col];
            }
        }
    }

    // ---- h_final from the last chunk's blocks
    if (ch == NCHUNK - 1) {
#pragma unroll
        for (int ii = 0; ii < 16; ++ii) {
            int v = tid * 16 + ii;
            int bl = v >> 8, u = v & 255;
            hfin[(size_t)(b0 + bl) * HIDD + u] = bf2f(sX[bl * XSTRIDE + OBS_DIMM + u]);
        }
    }
}

extern "C" void kernel_launch(void* const* d_in, const int* in_sizes, int n_in,
                              void* d_out, int out_size, void* d_ws, size_t ws_size,
                              hipStream_t stream) {
    const float* obs    = (const float*)d_in[0];
    const int*   isini  = (const int*)d_in[1];
    const float* hx     = (const float*)d_in[2];
    const float* W_in   = (const float*)d_in[3];
    const float* b_in   = (const float*)d_in[4];
    const float* W_ih   = (const float*)d_in[5];
    const float* b_ih   = (const float*)d_in[6];
    const float* W_hh   = (const float*)d_in[7];
    const float* b_hh   = (const float*)d_in[8];
    const float* W_out  = (const float*)d_in[9];
    const float* b_out  = (const float*)d_in[10];

    // workspace layout: W' bf16 | W_out' bf16 | b_x f32
    unsigned short* wsW  = (unsigned short*)d_ws;
    unsigned short* wsWo = wsW + KDIM * NGATE;        // 294912 elems
    float*          wsBx = (float*)(wsWo + 256 * 32); // 8192 elems

    float* outp = (float*)d_out;
    float* hfin = outp + (size_t)BBATCH * TTIME * LATT;

    prep_kernel<<<1187, 256, 0, stream>>>(W_in, b_in, W_ih, b_ih, W_hh, W_out, wsW, wsWo, wsBx);
    gru_kernel<<<512, 512, 0, stream>>>(obs, isini, hx, b_hh, b_out, wsW, wsWo, wsBx, outp, hfin);
}

// Round 6
// 666.811 us; speedup vs baseline: 2.5529x; 2.5529x over previous
//
#include <hip/hip_runtime.h>
#include <cstdint>
#include <cstddef>

// Problem constants
#define OBS_DIMM 128
#define PROJJ    64
#define HIDD     256
#define LATT     24
#define BBATCH   1024
#define TTIME    256
#define NGATE    768   // 3*HID
#define MBLK     16    // batches per block
#define CHUNK    64    // timesteps per block
#define NGROUP   64
#define NCHUNK   4
#define OSTR     136   // obs row stride (ushorts): 128 + 8 pad (16B-aligned, bank-skewed)
#define XSTR     72    // x row stride: 64 + 8 pad
#define HSTR     264   // h/mish row stride: 256 + 8 pad

using bf16x8 = __attribute__((ext_vector_type(8))) short;   // 8 bf16 in 4 VGPRs
using bf16x4 = __attribute__((ext_vector_type(4))) short;
using f32x4  = __attribute__((ext_vector_type(4))) float;

static __device__ __forceinline__ unsigned short f2bf(float f) {
    unsigned u = __builtin_bit_cast(unsigned, f);
    u += 0x7fffu + ((u >> 16) & 1u);          // RNE
    return (unsigned short)(u >> 16);
}
static __device__ __forceinline__ float bf2f(unsigned short h) {
    return __builtin_bit_cast(float, ((unsigned)h) << 16);
}
static __device__ __forceinline__ float fexp2(float x) { return __builtin_amdgcn_exp2f(x); }
static __device__ __forceinline__ float flog2(float x) { return __builtin_amdgcn_logf(x); }
static __device__ __forceinline__ float frcp (float x) { return __builtin_amdgcn_rcpf(x); }
static __device__ __forceinline__ float sigmoid_(float x) { return frcp(1.f + fexp2(-1.44269504f * x)); }
static __device__ __forceinline__ float tanh_(float x)    { return 1.f - 2.f * frcp(fexp2(2.88539008f * x) + 1.f); }

#define MFMA16(a, b, c) __builtin_amdgcn_mfma_f32_16x16x32_bf16((a), (b), (c), 0, 0, 0)

// ---------------------------------------------------------------------------
// Prep: bf16-swizzle all weights into MFMA B-fragment layouts.
// Gate-space decomposition (for W_hh / W_ih cols): n = g*256 + u,
//   u = w*32 + i*16 + c16  ->  wave w owns hidden units [32w, 32w+32).
// Fragment element: lane = q*16 + c16 holds k = kt*32 + q*8 + jj.
//   wsWhh: ((w*8 + kt)*6 + i*3 + g)*512 + lane*8 + jj     (k in 0..255)
//   wsWih: ((w*2 + kt)*6 + i*3 + g)*512 + lane*8 + jj     (k in 0..63, x-dim)
//   wsWin: (kt*4 + nt)*512 + lane*8 + jj                  (128x64)
//   wsWo : (nt*8 + kt)*512 + lane*8 + jj                  (256x32, cols>=24 zero)
//   wsBx : b_in@W_ih + b_ih (fp32, 768)
// ---------------------------------------------------------------------------
__global__ void prep_kernel(const float* __restrict__ W_in, const float* __restrict__ b_in,
                            const float* __restrict__ W_ih, const float* __restrict__ b_ih,
                            const float* __restrict__ W_hh, const float* __restrict__ W_out,
                            unsigned short* __restrict__ wsWhh, unsigned short* __restrict__ wsWih,
                            unsigned short* __restrict__ wsWin, unsigned short* __restrict__ wsWo,
                            float* __restrict__ wsBx) {
    int idx = blockIdx.x * 256 + threadIdx.x;
    if (idx < 196608) {                       // W_hh 256x768
        int k = idx / NGATE, n = idx - k * NGATE;
        int kt = k >> 5, q = (k >> 3) & 3, jj = k & 7;
        int g = n >> 8, u = n & 255, w = u >> 5, i = (u >> 4) & 1, c16 = u & 15;
        int lane = q * 16 + c16;
        wsWhh[((w * 8 + kt) * 6 + i * 3 + g) * 512 + lane * 8 + jj] = f2bf(W_hh[k * NGATE + n]);
    } else if (idx < 196608 + 49152) {        // W_ih 64x768
        int i2 = idx - 196608;
        int k = i2 / NGATE, n = i2 - k * NGATE;
        int kt = k >> 5, q = (k >> 3) & 3, jj = k & 7;
        int g = n >> 8, u = n & 255, w = u >> 5, i = (u >> 4) & 1, c16 = u & 15;
        int lane = q * 16 + c16;
        wsWih[((w * 2 + kt) * 6 + i * 3 + g) * 512 + lane * 8 + jj] = f2bf(W_ih[k * NGATE + n]);
    } else if (idx < 196608 + 49152 + 8192) { // W_in 128x64
        int i3 = idx - (196608 + 49152);
        int k = i3 >> 6, n = i3 & 63;
        int kt = k >> 5, q = (k >> 3) & 3, jj = k & 7;
        int nt = n >> 4, nl = n & 15;
        wsWin[(kt * 4 + nt) * 512 + (q * 16 + nl) * 8 + jj] = f2bf(W_in[k * PROJJ + n]);
    } else if (idx < 196608 + 49152 + 8192 + 8192) { // W_out 256x32
        int i4 = idx - (196608 + 49152 + 8192);
        int k = i4 >> 5, n = i4 & 31;
        float s = (n < LATT) ? W_out[k * LATT + n] : 0.f;
        int kt = k >> 5, q = (k >> 3) & 3, jj = k & 7;
        int nt = n >> 4, nl = n & 15;
        wsWo[(nt * 8 + kt) * 512 + (q * 16 + nl) * 8 + jj] = f2bf(s);
    } else if (idx < 196608 + 49152 + 8192 + 8192 + NGATE) {
        int n = idx - (196608 + 49152 + 8192 + 8192);
        float s = b_ih[n];
        for (int j = 0; j < PROJJ; ++j) s += b_in[j] * W_ih[j * NGATE + n];
        wsBx[n] = s;
    }
}

// ---------------------------------------------------------------------------
// Persistent-weight GRU: grid = 64 batch-groups x 4 time-chunks = 256 blocks.
// W_hh lives in VGPRs (48 B-fragments/wave, loaded ONCE); W_ih/W_in/W_out in
// LDS. Zero per-step global weight traffic. Per step: stage obs -> x-proj
// (16 MFMAs) -> gate GEMM K=320 (60 MFMAs/wave) -> wave-local gates ->
// mish + out-proj -> 2-step staged coalesced output flush.
// ---------------------------------------------------------------------------
__global__ __launch_bounds__(512, 2)
void gru_kernel(const float* __restrict__ obs, const int* __restrict__ is_init,
                const float* __restrict__ hx, const float* __restrict__ b_hh,
                const float* __restrict__ b_out,
                const unsigned short* __restrict__ wsWhh, const unsigned short* __restrict__ wsWih,
                const unsigned short* __restrict__ wsWin, const unsigned short* __restrict__ wsWo,
                const float* __restrict__ wsBx,
                float* __restrict__ out, float* __restrict__ hfin) {
    __shared__ __align__(16) unsigned short sWih[49152];        // 96 KB
    __shared__ __align__(16) unsigned short sWin[8192];         // 16 KB
    __shared__ __align__(16) unsigned short sWo[8192];          // 16 KB
    __shared__ __align__(16) unsigned short sH[MBLK * HSTR];    // h state bf16
    __shared__ __align__(16) unsigned short sM[MBLK * HSTR];    // mish(h) bf16
    __shared__ __align__(16) unsigned short sObs[MBLK * OSTR];  // obs_t bf16
    __shared__ __align__(16) unsigned short sX[MBLK * XSTR];    // x_t bf16
    __shared__ __align__(16) float sOut[2 * MBLK * LATT];       // 2-step out stage
    __shared__ int sT;

    const int tid  = threadIdx.x;
    const int w    = tid >> 6;
    const int lane = tid & 63;
    const int q    = lane >> 4;
    const int c16  = lane & 15;
    const int bid  = blockIdx.x;
    const int g    = bid & (NGROUP - 1);
    const int ch   = bid >> 6;
    const int b0   = g * MBLK;
    const int t0   = ch * CHUNK;

    // ---- persistent W_hh fragments: 48 x bf16x8 = 192 VGPRs, loaded once ----
    const unsigned short* whh_p = wsWhh + (size_t)w * 24576 + lane * 8;
    bf16x8 Whh[48];
#pragma unroll
    for (int f = 0; f < 48; ++f)
        Whh[f] = *(const bf16x8*)(whh_p + (size_t)f * 512);

    // ---- stage W_ih' / W_in' / W_out' into LDS ----
    // 512 thr x 16 B = 8 KB per iteration: sWih 96 KB -> 12 iters,
    // sWin/sWo 16 KB -> 2 iters. (R5 crash: these bounds were 2x too big ->
    // OOB LDS writes -> HSA abort.)
    {
        const uint4* s1 = (const uint4*)wsWih; uint4* d1 = (uint4*)sWih;
#pragma unroll
        for (int r = 0; r < 12; ++r) d1[r * 512 + tid] = s1[r * 512 + tid];
        const uint4* s2 = (const uint4*)wsWin; uint4* d2 = (uint4*)sWin;
#pragma unroll
        for (int r = 0; r < 2; ++r) d2[r * 512 + tid] = s2[r * 512 + tid];
        const uint4* s3 = (const uint4*)wsWo;  uint4* d3 = (uint4*)sWo;
#pragma unroll
        for (int r = 0; r < 2; ++r) d3[r * 512 + tid] = s3[r * 512 + tid];
    }

    // per-wave gate biases (col u = (2w+i)*16 + c16)
    float bR[2], bZ[2], bXN[2], bHN[2];
#pragma unroll
    for (int i = 0; i < 2; ++i) {
        int u = (2 * w + i) * 16 + c16;
        bR[i]  = wsBx[u] + b_hh[u];
        bZ[i]  = wsBx[HIDD + u] + b_hh[HIDD + u];
        bXN[i] = wsBx[2 * HIDD + u];
        bHN[i] = b_hh[2 * HIDD + u];
    }
    float bOutV;
    {
        int col = (w & 1) * 16 + c16;
        bOutV = (col < LATT) ? b_out[col] : 0.f;
    }

    // ---- find start time: most recent reset before t0 (min over group) ----
    if (tid == 0) sT = (ch == 0) ? 0 : 0x7fffffff;
    __syncthreads();
    if (ch > 0 && tid < MBLK) {
        int b = b0 + tid, fs = 0;
        for (int t = t0 - 1; t > 0; --t) {
            if (is_init[b * TTIME + t] != 0) { fs = t; break; }
        }
        atomicMin(&sT, fs);
    }
    __syncthreads();
    const int tstart = sT;

    // ---- init h: hx if starting at t=0, else 0 ----
    if (tid < 256) {
        int bl = tid >> 4, part = tid & 15;
        bf16x8 v0 = {0, 0, 0, 0, 0, 0, 0, 0}, v1 = {0, 0, 0, 0, 0, 0, 0, 0};
        if (tstart == 0) {
            const float* hp = hx + (size_t)(b0 + bl) * HIDD + part * 16;
#pragma unroll
            for (int ii = 0; ii < 8; ++ii) {
                v0[ii] = (short)f2bf(hp[ii]);
                v1[ii] = (short)f2bf(hp[8 + ii]);
            }
        }
        *(bf16x8*)(sH + bl * HSTR + part * 16)     = v0;
        *(bf16x8*)(sH + bl * HSTR + part * 16 + 8) = v1;
    }
    __syncthreads();

    const unsigned short* wihp = sWih + w * 6144 + lane * 8;
    const int tend = t0 + CHUNK;

    for (int t = tstart; t < tend; ++t) {
        // ---- phase 1: stage obs_t bf16 (all 512 thr); reset-mask h ----
        {
            int bl = tid >> 5, part = tid & 31;
            const float* op = obs + ((size_t)((b0 + bl) * TTIME + t)) * OBS_DIMM + part * 4;
            float4 a = *(const float4*)op;
            bf16x4 pk;
            pk[0] = (short)f2bf(a.x); pk[1] = (short)f2bf(a.y);
            pk[2] = (short)f2bf(a.z); pk[3] = (short)f2bf(a.w);
            *(bf16x4*)(sObs + bl * OSTR + part * 4) = pk;
        }
        if (tid < 256) {
            int bl = tid >> 4, part = tid & 15;
            if (is_init[(b0 + bl) * TTIME + t] != 0) {
                bf16x8 z8 = {0, 0, 0, 0, 0, 0, 0, 0};
                *(bf16x8*)(sH + bl * HSTR + part * 16)     = z8;
                *(bf16x8*)(sH + bl * HSTR + part * 16 + 8) = z8;
            }
        }
        __syncthreads();                       // B1: obs staged, h masked

        // ---- phase 1b: x_t[16,64] = obs_t @ W_in  (waves 0..3, ntile = w) ----
        if (w < 4) {
            f32x4 xa = {0.f, 0.f, 0.f, 0.f};
#pragma unroll
            for (int kt = 0; kt < 4; ++kt) {
                bf16x8 a  = *(const bf16x8*)(sObs + c16 * OSTR + kt * 32 + q * 8);
                bf16x8 bf = *(const bf16x8*)(sWin + (kt * 4 + w) * 512 + lane * 8);
                xa = MFMA16(a, bf, xa);
            }
#pragma unroll
            for (int r = 0; r < 4; ++r)
                sX[(q * 4 + r) * XSTR + w * 16 + c16] = f2bf(xa[r]);
        }
        __syncthreads();                       // B2: x ready

        // ---- phase 2: gates[16,768] = [x|h] @ [W_ih;W_hh], K=320 ----
        f32x4 accR[2], accZ[2], accXN[2], accHN[2];
#pragma unroll
        for (int i = 0; i < 2; ++i) {
            accR[i]  = (f32x4){bR[i], bR[i], bR[i], bR[i]};
            accZ[i]  = (f32x4){bZ[i], bZ[i], bZ[i], bZ[i]};
            accXN[i] = (f32x4){bXN[i], bXN[i], bXN[i], bXN[i]};
            accHN[i] = (f32x4){bHN[i], bHN[i], bHN[i], bHN[i]};
        }
#pragma unroll
        for (int kt = 0; kt < 2; ++kt) {       // x part (W_ih from LDS)
            bf16x8 a = *(const bf16x8*)(sX + c16 * XSTR + kt * 32 + q * 8);
#pragma unroll
            for (int i = 0; i < 2; ++i) {
                accR[i]  = MFMA16(a, *(const bf16x8*)(wihp + (kt * 6 + i * 3 + 0) * 512), accR[i]);
                accZ[i]  = MFMA16(a, *(const bf16x8*)(wihp + (kt * 6 + i * 3 + 1) * 512), accZ[i]);
                accXN[i] = MFMA16(a, *(const bf16x8*)(wihp + (kt * 6 + i * 3 + 2) * 512), accXN[i]);
            }
        }
#pragma unroll
        for (int kt = 0; kt < 8; ++kt) {       // h part (W_hh from REGISTERS)
            bf16x8 a = *(const bf16x8*)(sH + c16 * HSTR + kt * 32 + q * 8);
#pragma unroll
            for (int i = 0; i < 2; ++i) {
                accR[i]  = MFMA16(a, Whh[kt * 6 + i * 3 + 0], accR[i]);
                accZ[i]  = MFMA16(a, Whh[kt * 6 + i * 3 + 1], accZ[i]);
                accHN[i] = MFMA16(a, Whh[kt * 6 + i * 3 + 2], accHN[i]);
            }
        }
        __syncthreads();                       // B3: all A-reads of sX/sH done

        // ---- phase 3: wave-local gates + h update (+ mish when emitting) ----
        const bool emit = (t >= t0);
#pragma unroll
        for (int i = 0; i < 2; ++i) {
            int u = (2 * w + i) * 16 + c16;
#pragma unroll
            for (int r = 0; r < 4; ++r) {
                int bl = q * 4 + r;
                float rr = sigmoid_(accR[i][r]);
                float zz = sigmoid_(accZ[i][r]);
                float nn = tanh_(accXN[i][r] + rr * accHN[i][r]);
                float hOld = bf2f(sH[bl * HSTR + u]);
                float hN = (1.f - zz) * nn + zz * hOld;
                sH[bl * HSTR + u] = f2bf(hN);
                if (emit) {
                    float sp = 0.69314718f * flog2(1.f + fexp2(1.44269504f * hN));
                    sM[bl * HSTR + u] = f2bf(hN * tanh_(sp));
                }
            }
        }
        __syncthreads();                       // B4: h_new + mish visible

        // ---- phase 4: out-proj (waves 0..1) + 2-step staged flush ----
        if (emit) {
            int dt = (t - t0) & 1;
            if (w < 2) {
                f32x4 acc = (f32x4){bOutV, bOutV, bOutV, bOutV};
#pragma unroll
                for (int kt = 0; kt < 8; ++kt) {
                    bf16x8 a  = *(const bf16x8*)(sM + c16 * HSTR + kt * 32 + q * 8);
                    bf16x8 wf = *(const bf16x8*)(sWo + (w * 8 + kt) * 512 + lane * 8);
                    acc = MFMA16(a, wf, acc);
                }
                int col = w * 16 + c16;
                if (col < LATT) {
#pragma unroll
                    for (int r = 0; r < 4; ++r)
                        sOut[(dt * MBLK + q * 4 + r) * LATT + col] = acc[r];
                }
            }
            if (dt == 1) {
                __syncthreads();               // B4f: sOut complete
                int tf = t - 1;
#pragma unroll
                for (int p = 0; p < 2; ++p) {
                    int v = p * 512 + tid;     // 768 floats: 16 batches x 2 steps x 24
                    if (v < 768) {
                        int b = v / 48, rr2 = v - 48 * b;       // rr2 = dtq*24 + col
                        int dtq = rr2 >= LATT ? 1 : 0, col = rr2 - LATT * dtq;
                        out[((size_t)(b0 + b) * TTIME + tf) * LATT + rr2] =
                            sOut[(dtq * MBLK + b) * LATT + col];
                    }
                }
            }
        }
    }

    // ---- h_final from the last chunk's blocks ----
    if (ch == NCHUNK - 1) {
#pragma unroll
        for (int p = 0; p < 8; ++p) {
            int v = p * 512 + tid;             // 4096 = 16 x 256
            int bl = v >> 8, u = v & 255;
            hfin[(size_t)(b0 + bl) * HIDD + u] = bf2f(sH[bl * HSTR + u]);
        }
    }
}

extern "C" void kernel_launch(void* const* d_in, const int* in_sizes, int n_in,
                              void* d_out, int out_size, void* d_ws, size_t ws_size,
                              hipStream_t stream) {
    const float* obs    = (const float*)d_in[0];
    const int*   isini  = (const int*)d_in[1];
    const float* hx     = (const float*)d_in[2];
    const float* W_in   = (const float*)d_in[3];
    const float* b_in   = (const float*)d_in[4];
    const float* W_ih   = (const float*)d_in[5];
    const float* b_ih   = (const float*)d_in[6];
    const float* W_hh   = (const float*)d_in[7];
    const float* b_hh   = (const float*)d_in[8];
    const float* W_out  = (const float*)d_in[9];
    const float* b_out  = (const float*)d_in[10];

    // workspace: Whh' | Wih' | Win' | Wo' (bf16) | b_x (f32)  (~527 KB)
    unsigned short* wsWhh = (unsigned short*)d_ws;
    unsigned short* wsWih = wsWhh + 196608;
    unsigned short* wsWin = wsWih + 49152;
    unsigned short* wsWo  = wsWin + 8192;
    float*          wsBx  = (float*)(wsWo + 8192);

    float* outp = (float*)d_out;
    float* hfin = outp + (size_t)BBATCH * TTIME * LATT;

    prep_kernel<<<1027, 256, 0, stream>>>(W_in, b_in, W_ih, b_ih, W_hh, W_out,
                                          wsWhh, wsWih, wsWin, wsWo, wsBx);
    gru_kernel<<<256, 512, 0, stream>>>(obs, isini, hx, b_hh, b_out,
                                        wsWhh, wsWih, wsWin, wsWo, wsBx, outp, hfin);
}